// Round 2
// baseline (552.717 us; speedup 1.0000x reference)
//
#include <hip/hip_runtime.h>

#ifndef INV_CELL_H
#define INV_CELL_H 20.0f
#endif

// Cubic B-spline basis + derivative for stencil offset idx in {0,1,2,3},
// where the spline argument is x = f + 1 - idx, f = frac(rel) in [0,1).
// Branches (from the reference's jnp.select) collapse per-offset:
//   idx=0: x in [1,2)   -> b = (2-x)^3/6          = g^3/6,             db = -h*g^2/2
//   idx=1: x in [0,1)   -> b = 2/3 - x^2 + x^3/2  (x=f),               db = -h*f*(2-1.5f)
//   idx=2: x in [-1,0)  -> b = 2/3 - g^2 + g^3/2  (g=1-f),             db = +h*g*(2-1.5g)
//   idx=3: x in [-2,-1) -> b = (2+x)^3/6          = f^3/6,             db = +h*f^2/2
// All selects are lane-derived constants -> cndmask, no divergence.
__device__ __forceinline__ void spline_eval(float f, float g, int idx,
                                            float& b, float& db) {
    float u  = (idx & 1) ? f : g;          // idx 0,2 use g; idx 1,3 use f
    float u2 = u * u;
    float u3 = u2 * u;
    bool outer = (idx == 0) || (idx == 3);
    float b_out = u3 * (1.0f / 6.0f);
    float b_in  = fmaf(0.5f, u3, fmaf(-1.0f, u2, 2.0f / 3.0f));
    b = outer ? b_out : b_in;
    float m_out = 0.5f * u2;
    float m_in  = u * fmaf(-1.5f, u, 2.0f);
    float mag = outer ? m_out : m_in;
    float sgn = (idx >= 2) ? INV_CELL_H : -INV_CELL_H;
    db = mag * sgn;
}

// One wave (64 lanes) per particle; lane = m = i*16 + j*4 + k matches the
// reference meshgrid(ij) flattening. Compute per-lane, stage the particle's
// 1024-B output block in LDS, then re-emit as 64 aligned float4 stores
// (lanes 0-15 -> shapef[64], lanes 16-63 -> grad[64][3]) so every store
// instruction covers fully-written 64-B lines (no partial-line writes).
__global__ void __launch_bounds__(256)
cubic_shapefn_kernel(const float* __restrict__ pos,
                     float* __restrict__ shapef,   // [N][64]
                     float* __restrict__ grad,     // [N][64][3]
                     int N) {
    __shared__ float lds[4][256];                  // per-wave: [0,64) s, [64,256) grad
    int wslot = threadIdx.x >> 6;
    int wave  = blockIdx.x * 4 + wslot;
    int lane  = threadIdx.x & 63;
    if (wave >= N) return;                         // N=500k -> 125000 full blocks, no tail

    float px = pos[(size_t)wave * 3 + 0];
    float py = pos[(size_t)wave * 3 + 1];
    float pz = pos[(size_t)wave * 3 + 2];

    float rx = px * INV_CELL_H, ry = py * INV_CELL_H, rz = pz * INV_CELL_H;
    float fx = rx - floorf(rx), fy = ry - floorf(ry), fz = rz - floorf(rz);
    float gx = 1.0f - fx,       gy = 1.0f - fy,       gz = 1.0f - fz;

    int i = (lane >> 4) & 3;
    int j = (lane >> 2) & 3;
    int k = lane & 3;

    float bx, dbx, by, dby, bz, dbz;
    spline_eval(fx, gx, i, bx, dbx);
    spline_eval(fy, gy, j, by, dby);
    spline_eval(fz, gz, k, bz, dbz);

    float pyz = by * bz;
    float s   = bx * pyz;
    float gxv = dbx * pyz;
    float gyv = dby * (bx * bz);
    float gzv = dbz * (bx * by);

    float* L = lds[wslot];
    L[lane]                = s;     // stride-1 dwords: 2-way bank alias, free
    L[64 + 3 * lane + 0]   = gxv;   // stride-3 dwords: gcd(3,32)=1 -> 2-way, free
    L[64 + 3 * lane + 1]   = gyv;
    L[64 + 3 * lane + 2]   = gzv;
    __syncthreads();

    // Re-emit as 64 float4 stores: lanes 0-15 cover shapef (256 B),
    // lanes 16-63 cover grad (768 B). Branchless pointer select.
    bool is_s = lane < 16;
    int  q    = is_s ? lane : (lane - 16);
    const float4* src = is_s ? ((const float4*)L) + q
                             : ((const float4*)(L + 64)) + q;
    float4* dst = is_s ? ((float4*)(shapef + (size_t)wave * 64)) + q
                       : ((float4*)(grad   + (size_t)wave * 192)) + q;
    *dst = *src;
}

extern "C" void kernel_launch(void* const* d_in, const int* in_sizes, int n_in,
                              void* d_out, int out_size, void* d_ws, size_t ws_size,
                              hipStream_t stream) {
    const float* pos = (const float*)d_in[0];
    int N = in_sizes[0] / 3;                       // 500,000
    float* shapef = (float*)d_out;                 // [N*64]
    float* grad   = shapef + (size_t)N * 64;       // [N*64*3]
    int blocks = (N + 3) / 4;                      // 4 waves/block, 1 particle/wave
    cubic_shapefn_kernel<<<blocks, 256, 0, stream>>>(pos, shapef, grad, N);
}